// Round 2
// baseline (191.740 us; speedup 1.0000x reference)
//
#include <hip/hip_runtime.h>
#include <math.h>

#define TLEN 8192
#define HALF 4096
#define NTH  256

__device__ __forceinline__ int padi(int i) { return i + (i >> 5); }

__global__ __launch_bounds__(NTH) void hurst_kernel(const float* __restrict__ x,
                                                    float* __restrict__ out) {
    // staging buffer for one 4096-element half (padded: +1 word per 32)
    __shared__ float SB[HALF + (HALF >> 5)];   // 4224 floats = 16896 B
    __shared__ float Sp[513];                  // exclusive prefix of 16-elem segment sums
    __shared__ float SSp[513];                 // exclusive prefix of segment sumsq
    __shared__ float wsum[4], wssq[4];         // per-wave scan totals
    __shared__ float meanL[62], SL[62];        // per-chunk mean / clamped std (all scales)
    __shared__ float pmax[72], pmin[72];       // per-chunk (xwave-partial) max/min of h
    __shared__ float rsb[62];                  // per-chunk R/S

    const int t = threadIdx.x;
    const int lane = t & 63;
    const int wave = t >> 6;
    const float* xr = x + (long long)blockIdx.x * TLEN;

    // P[h][k] = global inclusive prefix Q at position h*4096 + 16*t + k  (registers)
    float P[2][16];
    float carry_s = 0.f, carry_q = 0.f;

    #pragma unroll
    for (int h = 0; h < 2; ++h) {
        // ---- stage half h: coalesced float4 loads -> padded LDS ----
        const float* xh = xr + h * HALF;
        #pragma unroll
        for (int j = 0; j < 4; ++j) {
            int p = j * 1024 + t * 4;
            float4 v = *reinterpret_cast<const float4*>(xh + p);
            SB[padi(p)]     = v.x;
            SB[padi(p + 1)] = v.y;
            SB[padi(p + 2)] = v.z;
            SB[padi(p + 3)] = v.w;
        }
        __syncthreads();

        // ---- per-thread 16-elem segment: raw values + sum + sumsq ----
        const int base = 16 * t + (t >> 1);    // padi(16*t), no pad crossing in 16
        float rr[16];
        float ssum = 0.f, ssq = 0.f;
        #pragma unroll
        for (int k = 0; k < 16; ++k) {
            float v = SB[base + k];
            rr[k] = v;
            ssum += v;
            ssq = fmaf(v, v, ssq);
        }

        // ---- wave-inclusive scan of (sum, sumsq) over segment order ----
        float v1 = ssum, v2 = ssq;
        #pragma unroll
        for (int d = 1; d < 64; d <<= 1) {
            float u1 = __shfl_up(v1, d, 64);
            float u2 = __shfl_up(v2, d, 64);
            if (lane >= d) { v1 += u1; v2 += u2; }
        }
        if (lane == 63) { wsum[wave] = v1; wssq[wave] = v2; }
        __syncthreads();
        float w0 = wsum[0], w1 = wsum[1], w2 = wsum[2], w3 = wsum[3];
        float q0 = wssq[0], q1 = wssq[1], q2 = wssq[2], q3 = wssq[3];
        float woff1 = carry_s, woff2 = carry_q;
        if (wave > 0) { woff1 += w0; woff2 += q0; }
        if (wave > 1) { woff1 += w1; woff2 += q1; }
        if (wave > 2) { woff1 += w2; woff2 += q2; }
        carry_s += w0 + w1 + w2 + w3;          // running grand totals across halves
        carry_q += q0 + q1 + q2 + q3;

        float ex1 = woff1 + (v1 - ssum);       // global exclusive prefix (segment level)
        float ex2 = woff2 + (v2 - ssq);
        Sp[h * 256 + t]  = ex1;
        SSp[h * 256 + t] = ex2;

        // ---- element-level inclusive prefix, kept in registers ----
        float run = ex1;
        #pragma unroll
        for (int k = 0; k < 16; ++k) { run += rr[k]; P[h][k] = run; }
    }
    if (t == 0) { Sp[512] = carry_s; SSp[512] = carry_q; }
    __syncthreads();

    // ---- all 62 chunk (mean, std) in one shot: t < 62 covers scale si, chunk ci ----
    if (t < 62) {
        int si, ci;
        if (t < 32)      { si = 0; ci = t; }
        else if (t < 48) { si = 1; ci = t - 32; }
        else if (t < 56) { si = 2; ci = t - 48; }
        else if (t < 60) { si = 3; ci = t - 56; }
        else             { si = 4; ci = t - 60; }
        int g = 16 << si;                      // segments per chunk
        int a = ci * g, b = a + g;
        float s_f = (float)(256 << si);
        float sum = Sp[b] - Sp[a];
        float sq  = SSp[b] - SSp[a];
        float m = sum / s_f;
        float var = (sq - s_f * m * m) / (s_f - 1.0f);
        meanL[t] = m;
        SL[t] = fmaxf(sqrtf(fmaxf(var, 0.f)), 1e-8f);
    }
    __syncthreads();

    // ---- per-scale max/min of h = Q[i] - (i+1)*m, register-resident ----
    #pragma unroll
    for (int si = 0; si < 5; ++si) {
        const int lg = 4 + si;
        const int g = 1 << lg;                 // threads per chunk per half
        const int OFF  = (si == 0) ? 0 : (si == 1) ? 32 : (si == 2) ? 48 : (si == 3) ? 56 : 60;
        const int POFF = (si == 0) ? 0 : (si == 1) ? 32 : (si == 2) ? 48 : (si == 3) ? 56 : 64;
        const int c0 = t >> lg;                // chunk id (within scale), half 0
        const int c1 = (256 >> lg) + c0;       // chunk id, half 1
        const float m0 = meanL[OFF + c0];
        const float m1 = meanL[OFF + c1];

        float mx0 = -INFINITY, mn0 = INFINITY, mx1 = -INFINITY, mn1 = INFINITY;
        #pragma unroll
        for (int k = 0; k < 16; ++k) {
            float g0 = fmaf(-m0, (float)k, P[0][k]);   // Q - k*m (chunk-const part added below)
            float g1 = fmaf(-m1, (float)k, P[1][k]);
            mx0 = fmaxf(mx0, g0); mn0 = fminf(mn0, g0);
            mx1 = fmaxf(mx1, g1); mn1 = fminf(mn1, g1);
        }
        // per-thread offset: -(rel_pos_of_k0 + 1) * m  (chunk-uniform part cancels in R)
        const float rb1 = (float)(16 * (t & (g - 1)) + 1);
        mx0 -= rb1 * m0; mn0 -= rb1 * m0;
        mx1 -= rb1 * m1; mn1 -= rb1 * m1;

        // in-wave butterfly within the (aligned) chunk thread-group
        const int bw = (g < 64) ? g : 64;
        #pragma unroll
        for (int w = 1; w < bw; w <<= 1) {
            mx0 = fmaxf(mx0, __shfl_xor(mx0, w, 64));
            mn0 = fminf(mn0, __shfl_xor(mn0, w, 64));
            mx1 = fmaxf(mx1, __shfl_xor(mx1, w, 64));
            mn1 = fminf(mn1, __shfl_xor(mn1, w, 64));
        }
        if ((t & (bw - 1)) == 0) {
            const int pc  = (g > 64) ? (g >> 6) : 1;   // cross-wave partials per chunk
            const int sub = (t >> 6) & (pc - 1);
            pmax[POFF + c0 * pc + sub] = mx0;
            pmin[POFF + c0 * pc + sub] = mn0;
            pmax[POFF + c1 * pc + sub] = mx1;
            pmin[POFF + c1 * pc + sub] = mn1;
        }
    }
    __syncthreads();

    // ---- tail: per-chunk R/S, then per-scale mean + log, then H ----
    if (t < 62) {
        int si, ci;
        if (t < 32)      { si = 0; ci = t; }
        else if (t < 48) { si = 1; ci = t - 32; }
        else if (t < 56) { si = 2; ci = t - 48; }
        else if (t < 60) { si = 3; ci = t - 56; }
        else             { si = 4; ci = t - 60; }
        const int pc   = (si == 3) ? 2 : (si == 4) ? 4 : 1;
        const int POFF = (si == 0) ? 0 : (si == 1) ? 32 : (si == 2) ? 48 : (si == 3) ? 56 : 64;
        int bsl = POFF + ci * pc;
        float mx = pmax[bsl], mn = pmin[bsl];
        #pragma unroll 4
        for (int j = 1; j < pc; ++j) {
            mx = fmaxf(mx, pmax[bsl + j]);
            mn = fminf(mn, pmin[bsl + j]);
        }
        float R = mx - mn;
        rsb[t] = fmaxf(R / SL[t], 1e-8f);
    }
    __syncthreads();

    float lrv = 0.f;
    if (t < 5) {
        const int nc  = 32 >> t;
        const int OFF = (t == 0) ? 0 : (t == 1) ? 32 : (t == 2) ? 48 : (t == 3) ? 56 : 60;
        float s = 0.f;
        for (int j = 0; j < nc; ++j) s += rsb[OFF + j];
        lrv = logf(fmaxf(s / (float)nc, 1e-8f));
    }
    if (wave == 0) {
        float n0 = __shfl(lrv, 0, 64);
        float n1 = __shfl(lrv, 1, 64);
        float n3 = __shfl(lrv, 3, 64);
        float n4 = __shfl(lrv, 4, 64);
        if (lane == 0) {
            // centered ln(s) = (k-2)*ln2; H = num / (10*ln2^2), one ln2 cancels
            float H = (-2.f * n0 - n1 + n3 + 2.f * n4)
                      * (1.0f / (10.0f * 0.69314718055994530942f));
            H = fminf(fmaxf(H, 0.05f), 0.95f);
            out[blockIdx.x] = H;
        }
    }
}

extern "C" void kernel_launch(void* const* d_in, const int* in_sizes, int n_in,
                              void* d_out, int out_size, void* d_ws, size_t ws_size,
                              hipStream_t stream) {
    const float* x = (const float*)d_in[0];
    float* out = (float*)d_out;
    const int B = in_sizes[0] / TLEN;          // 4096 rows
    hurst_kernel<<<dim3(B), dim3(NTH), 0, stream>>>(x, out);
}

// Round 3
// 187.878 us; speedup vs baseline: 1.0206x; 1.0206x over previous
//
#include <hip/hip_runtime.h>
#include <math.h>

#define TLEN 8192
#define NTH  256

__global__ __launch_bounds__(NTH, 4) void hurst_kernel(const float* __restrict__ x,
                                                       float* __restrict__ out) {
    __shared__ float wsum[4], wssq[4];     // per-wave scan totals
    __shared__ float Sp8[33], SSp8[33];    // exclusive prefix at 256-elem boundaries
    __shared__ float meanL[62], SL[62];    // per-chunk mean / clamped std (all scales)
    __shared__ float pmax[4], pmin[4];     // scale-4 cross-wave partials
    __shared__ float rsb[62];              // per-chunk R/S

    const int t = threadIdx.x;
    const int lane = t & 63;
    const int wave = t >> 6;
    const float* xr = x + (long long)blockIdx.x * TLEN;
    const float4* xq = reinterpret_cast<const float4*>(xr);

    // ---- direct global load: thread t owns elems [32t, 32t+32) = one 128-B line ----
    float4 v[8];
    #pragma unroll
    for (int j = 0; j < 8; ++j) v[j] = xq[8 * t + j];

    // ---- local inclusive prefix (L) + sum + sumsq, all in registers ----
    float L[32];
    float run = 0.f, ssq = 0.f;
    #pragma unroll
    for (int j = 0; j < 8; ++j) {
        float a0 = v[j].x, a1 = v[j].y, a2 = v[j].z, a3 = v[j].w;
        run += a0; L[4*j+0] = run; ssq = fmaf(a0, a0, ssq);
        run += a1; L[4*j+1] = run; ssq = fmaf(a1, a1, ssq);
        run += a2; L[4*j+2] = run; ssq = fmaf(a2, a2, ssq);
        run += a3; L[4*j+3] = run; ssq = fmaf(a3, a3, ssq);
    }
    const float ssum = run;

    // ---- wave-inclusive scan of (sum, sumsq) across the 256 segments ----
    float v1 = ssum, v2 = ssq;
    #pragma unroll
    for (int d = 1; d < 64; d <<= 1) {
        float u1 = __shfl_up(v1, d, 64);
        float u2 = __shfl_up(v2, d, 64);
        if (lane >= d) { v1 += u1; v2 += u2; }
    }
    if (lane == 63) { wsum[wave] = v1; wssq[wave] = v2; }
    __syncthreads();                                         // B1

    float woff1 = 0.f, woff2 = 0.f;
    if (wave > 0) { woff1 += wsum[0]; woff2 += wssq[0]; }
    if (wave > 1) { woff1 += wsum[1]; woff2 += wssq[1]; }
    if (wave > 2) { woff1 += wsum[2]; woff2 += wssq[2]; }
    const float ex1 = woff1 + (v1 - ssum);   // sum of elems [0, 32t)
    const float ex2 = woff2 + (v2 - ssq);    // sumsq of elems [0, 32t)

    // 256-elem-boundary prefixes (only 33 values needed for all chunk stats)
    if ((t & 7) == 0) { Sp8[t >> 3] = ex1; SSp8[t >> 3] = ex2; }
    if (t == NTH - 1) { Sp8[32] = ex1 + ssum; SSp8[32] = ex2 + ssq; }

    // ---- global inclusive prefix, register-resident: P[k] = L[k] + ex1 ----
    #pragma unroll
    for (int k = 0; k < 32; ++k) L[k] += ex1;
    __syncthreads();                                         // B2

    // ---- all 62 chunk (mean, std) in one shot ----
    if (t < 62) {
        int si, ci;
        if (t < 32)      { si = 0; ci = t; }
        else if (t < 48) { si = 1; ci = t - 32; }
        else if (t < 56) { si = 2; ci = t - 48; }
        else if (t < 60) { si = 3; ci = t - 56; }
        else             { si = 4; ci = t - 60; }
        int a = ci << si, b = (ci + 1) << si;
        float s_f = (float)(256 << si);
        float sum = Sp8[b] - Sp8[a];
        float sq  = SSp8[b] - SSp8[a];
        float m = sum / s_f;
        float var = (sq - s_f * m * m) / (s_f - 1.0f);
        meanL[t] = m;
        SL[t] = fmaxf(sqrtf(fmaxf(var, 0.f)), 1e-8f);
    }
    __syncthreads();                                         // B3

    // ---- per-scale max/min of h = Q[i] - (i - chunk_start + 1)*m ----
    #pragma unroll
    for (int si = 0; si < 5; ++si) {
        const int lg = 3 + si;
        const int g = 8 << si;                 // threads per chunk: 8..128
        const int OFF = (si == 0) ? 0 : (si == 1) ? 32 : (si == 2) ? 48
                      : (si == 3) ? 56 : 60;
        const int c = t >> lg;                 // chunk id within scale
        const float m = meanL[OFF + c];
        const int rel = t & (g - 1);           // thread pos within chunk
        float acc = (float)(32 * rel + 1) * m; // m*(local_pos_of_k=0 + 1)
        float hmax = -INFINITY, hmin = INFINITY;
        #pragma unroll
        for (int k = 0; k < 32; ++k) {
            float h = L[k] - acc;
            acc += m;
            hmax = fmaxf(hmax, h);
            hmin = fminf(hmin, h);
        }
        const int bw = (g < 64) ? g : 64;
        #pragma unroll
        for (int w = 1; w < bw; w <<= 1) {
            hmax = fmaxf(hmax, __shfl_xor(hmax, w, 64));
            hmin = fminf(hmin, __shfl_xor(hmin, w, 64));
        }
        if (si < 4) {
            if (rel == 0) {
                float R = hmax - hmin;
                rsb[OFF + c] = fmaxf(R / SL[OFF + c], 1e-8f);
            }
        } else {
            if (lane == 0) { pmax[wave] = hmax; pmin[wave] = hmin; }
        }
    }
    __syncthreads();                                         // B4

    if (t < 2) {   // scale-4 chunks: merge the 2 wave partials each
        float mx = fmaxf(pmax[2 * t], pmax[2 * t + 1]);
        float mn = fminf(pmin[2 * t], pmin[2 * t + 1]);
        rsb[60 + t] = fmaxf((mx - mn) / SL[60 + t], 1e-8f);
    }
    __syncthreads();                                         // B5

    float lrv = 0.f;
    if (t < 5) {
        const int nc  = 32 >> t;
        const int OFF = (t == 0) ? 0 : (t == 1) ? 32 : (t == 2) ? 48
                      : (t == 3) ? 56 : 60;
        float s = 0.f;
        for (int j = 0; j < nc; ++j) s += rsb[OFF + j];
        lrv = logf(fmaxf(s / (float)nc, 1e-8f));
    }
    if (wave == 0) {
        float n0 = __shfl(lrv, 0, 64);
        float n1 = __shfl(lrv, 1, 64);
        float n3 = __shfl(lrv, 3, 64);
        float n4 = __shfl(lrv, 4, 64);
        if (lane == 0) {
            // centered ln(s) = (si-2)*ln2; H = num/(10*ln2^2), one ln2 cancels
            float H = (-2.f * n0 - n1 + n3 + 2.f * n4)
                      * (1.0f / (10.0f * 0.69314718055994530942f));
            H = fminf(fmaxf(H, 0.05f), 0.95f);
            out[blockIdx.x] = H;
        }
    }
}

extern "C" void kernel_launch(void* const* d_in, const int* in_sizes, int n_in,
                              void* d_out, int out_size, void* d_ws, size_t ws_size,
                              hipStream_t stream) {
    const float* x = (const float*)d_in[0];
    float* out = (float*)d_out;
    const int B = in_sizes[0] / TLEN;          // 4096 rows
    hurst_kernel<<<dim3(B), dim3(NTH), 0, stream>>>(x, out);
}